// Round 2
// baseline (313.902 us; speedup 1.0000x reference)
//
#include <hip/hip_runtime.h>
#include <stdint.h>

#define V_DIM 32000
#define M_TOT 4096      // B*S
#define NF 128          // 2*n_freq
#define NC 256          // channels
#define BM 128
#define BK 32
#define SSTR 130        // As slot stride per kg-plane: kg -> +8 banks, 2-way max (free)
#define THREADS 256

typedef __bf16 bf16x8 __attribute__((ext_vector_type(8)));
typedef float f32x4 __attribute__((ext_vector_type(4)));

__device__ __forceinline__ unsigned short f2bf(float f) {
  unsigned int u = __float_as_uint(f);
  u += 0x7FFFu + ((u >> 16) & 1u);
  return (unsigned short)(u >> 16);
}

__device__ __forceinline__ int4 pack8(float4 lo, float4 hi) {
  union { unsigned short us[8]; int4 v; } u;
  u.us[0] = f2bf(lo.x); u.us[1] = f2bf(lo.y);
  u.us[2] = f2bf(lo.z); u.us[3] = f2bf(lo.w);
  u.us[4] = f2bf(hi.x); u.us[5] = f2bf(hi.y);
  u.us[6] = f2bf(hi.z); u.us[7] = f2bf(hi.w);
  return u.v;
}

__device__ __forceinline__ void gll16(const unsigned short* g, unsigned short* l) {
  __builtin_amdgcn_global_load_lds(
      (const __attribute__((address_space(1))) void*)g,
      (__attribute__((address_space(3))) void*)l, 16, 0, 0);
}

// ---------------- Stage 0: DFT basis table, PRE-SWIZZLED to LDS staging order.
// Layout: slot id = chunk*512 + kg*128 + row, each slot = 8 bf16 elements
//   element e of slot -> T_logical[row][chunk*32 + kg*8 + e]
//   T_logical[f][v] = cos(2pi(f+1)v/V) for f<64, -sin(2pi(f-63)v/V) for f>=64
__global__ __launch_bounds__(256) void build_table(unsigned short* __restrict__ T) {
  int id = blockIdx.x * 256 + threadIdx.x;        // slot id
  if (id >= 512 * (V_DIM / BK)) return;           // 512000
  int c = id >> 9;
  int r = id & 511;
  int kg = r >> 7;
  int row = r & 127;
  int k = (row < 64) ? (row + 1) : (row - 63);
  bool is_cos = (row < 64);
  int vb = c * 32 + kg * 8;
  const float w0 = 6.283185307179586f / (float)V_DIM;
  union { unsigned short us[8]; int4 v; } u;
  #pragma unroll
  for (int e = 0; e < 8; ++e) {
    int m = (k * (vb + e)) % V_DIM;               // exact range reduction
    float s, cc;
    __sincosf((float)m * w0, &s, &cc);
    u.us[e] = f2bf(is_cos ? cc : -s);
  }
  *reinterpret_cast<int4*>(T + (size_t)id * 8) = u.v;
}

// ---------------- Stage 1: P[ks] = x_chunk @ T_chunk^T (bf16 MFMA, fp32 acc)
__global__ __launch_bounds__(THREADS, 3) void gemm1(
    const float* __restrict__ x, const unsigned short* __restrict__ T,
    float* __restrict__ P, int NS) {
  __shared__ __align__(16) unsigned short As[2][4 * SSTR * 8];  // 8320 B each
  __shared__ __align__(16) unsigned short Bs[2][512 * 8];       // 8192 B each

  // XCD-balanced swizzle: xcd j gets ks = {j, j+8, ...} over all mt
  const int b = blockIdx.x;
  const int j = b & 7, i = b >> 3;
  const int ks = j + 8 * (i >> 5);
  const int mt = i & 31;
  const int m0 = mt * BM;

  const int total_steps = V_DIM / BK;   // 1000
  const int base = total_steps / NS;
  const int rem = total_steps % NS;
  const int steps = base + (ks < rem ? 1 : 0);
  const int start = ks * base + (ks < rem ? ks : rem);

  const int t = threadIdx.x;
  const int lane = t & 63;
  const int wave = t >> 6;
  const int wm = wave >> 1, wn = wave & 1;
  const int kgl = lane >> 4, rl = lane & 15;

  const int kg_t = t & 3;
  const int row_t = t >> 2;
  const int slot0 = kg_t * SSTR + row_t;
  const int slot1 = slot0 + 64;

  const float* xa0 = x + (size_t)(m0 + row_t) * V_DIM + kg_t * 8 + (size_t)start * BK;
  const float* xa1 = xa0 + (size_t)64 * V_DIM;

  f32x4 acc[4][4];
  #pragma unroll
  for (int a = 0; a < 4; ++a)
    #pragma unroll
    for (int c = 0; c < 4; ++c)
      acc[a][c] = (f32x4){0.f, 0.f, 0.f, 0.f};

  float4 sa[4], sb[4];  // two named register stage sets (x data), no runtime indexing

  // ---- prologue: stage step 0 into buf0, preload x(1) into sb
  {
    sa[0] = *reinterpret_cast<const float4*>(xa0);
    sa[1] = *reinterpret_cast<const float4*>(xa0 + 4);
    sa[2] = *reinterpret_cast<const float4*>(xa1);
    sa[3] = *reinterpret_cast<const float4*>(xa1 + 4);
    const unsigned short* tc = T + (size_t)start * 4096;
    gll16(tc + (size_t)(wave * 128 + lane) * 8, &Bs[0][(wave * 128) * 8]);
    gll16(tc + (size_t)(wave * 128 + 64 + lane) * 8, &Bs[0][(wave * 128 + 64) * 8]);
    *reinterpret_cast<int4*>(&As[0][slot0 * 8]) = pack8(sa[0], sa[1]);
    *reinterpret_cast<int4*>(&As[0][slot1 * 8]) = pack8(sa[2], sa[3]);
    if (steps > 1) {
      sb[0] = *reinterpret_cast<const float4*>(xa0 + BK);
      sb[1] = *reinterpret_cast<const float4*>(xa0 + BK + 4);
      sb[2] = *reinterpret_cast<const float4*>(xa1 + BK);
      sb[3] = *reinterpret_cast<const float4*>(xa1 + BK + 4);
    }
    __syncthreads();
  }

#define STEP(CUR, NXT, RL, RW)                                                \
  {                                                                           \
    if (s + 2 < steps) { /* issue x loads 2 steps ahead, earliest in step */  \
      const float* xp = xa0 + (size_t)(s + 2) * BK;                           \
      const float* xq = xa1 + (size_t)(s + 2) * BK;                           \
      RL[0] = *reinterpret_cast<const float4*>(xp);                           \
      RL[1] = *reinterpret_cast<const float4*>(xp + 4);                       \
      RL[2] = *reinterpret_cast<const float4*>(xq);                           \
      RL[3] = *reinterpret_cast<const float4*>(xq + 4);                       \
    }                                                                         \
    if (s + 1 < steps) { /* stage step s+1 into NXT: B direct-to-LDS, A regs */ \
      const unsigned short* tc = T + (size_t)(start + s + 1) * 4096;          \
      gll16(tc + (size_t)(wave * 128 + lane) * 8, &Bs[NXT][(wave * 128) * 8]);\
      gll16(tc + (size_t)(wave * 128 + 64 + lane) * 8,                        \
            &Bs[NXT][(wave * 128 + 64) * 8]);                                 \
      *reinterpret_cast<int4*>(&As[NXT][slot0 * 8]) = pack8(RW[0], RW[1]);    \
      *reinterpret_cast<int4*>(&As[NXT][slot1 * 8]) = pack8(RW[2], RW[3]);    \
    }                                                                         \
    bf16x8 bv[4];                                                             \
    _Pragma("unroll")                                                         \
    for (int nf = 0; nf < 4; ++nf)                                            \
      bv[nf] = *reinterpret_cast<const bf16x8*>(                              \
          &Bs[CUR][(kgl * 128 + wn * 64 + nf * 16 + rl) * 8]);                \
    _Pragma("unroll")                                                         \
    for (int mf = 0; mf < 4; ++mf) {                                          \
      bf16x8 av = *reinterpret_cast<const bf16x8*>(                           \
          &As[CUR][(kgl * SSTR + wm * 64 + mf * 16 + rl) * 8]);               \
      _Pragma("unroll")                                                       \
      for (int nf = 0; nf < 4; ++nf)                                          \
        acc[mf][nf] = __builtin_amdgcn_mfma_f32_16x16x32_bf16(                \
            av, bv[nf], acc[mf][nf], 0, 0, 0);                                \
    }                                                                         \
    __syncthreads();                                                          \
  }

  int s = 0;
  while (true) {
    STEP(0, 1, sa, sb)      // even step: consumes buf0; sb holds x(s+1); loads sa=x(s+2)
    if (++s >= steps) break;
    STEP(1, 0, sb, sa)      // odd step
    if (++s >= steps) break;
  }
#undef STEP

  // ---- epilogue: partial tile [128 x 128] for this k-split
  float* Pp = P + ((size_t)ks * M_TOT + m0) * NF;
  const int r0 = (lane >> 4) * 4;
  const int col = lane & 15;
  #pragma unroll
  for (int mf = 0; mf < 4; ++mf)
    #pragma unroll
    for (int nf = 0; nf < 4; ++nf)
      #pragma unroll
      for (int q = 0; q < 4; ++q) {
        int row = wm * 64 + mf * 16 + r0 + q;
        int n = wn * 64 + nf * 16 + col;
        Pp[(size_t)row * NF + n] = acc[mf][nf][q];
      }
}

// ---------------- Stage 2: out = (sum_s P[s]) @ W^T ----------------
__global__ __launch_bounds__(256) void gemm2(
    const float* __restrict__ P, const float* __restrict__ W,
    float* __restrict__ out, int NS) {
  __shared__ __align__(16) float Xr[8][NF];
  const int mb = blockIdx.x * 8;
  const int t = threadIdx.x;

  #pragma unroll
  for (int i = 0; i < 4; ++i) {
    int idx = t + i * 256;           // 0..1023 = 8 rows x 128 freqs
    int r = idx >> 7, f = idx & 127;
    float s = 0.f;
    for (int sp = 0; sp < NS; ++sp)
      s += P[((size_t)sp * M_TOT + mb + r) * NF + f];
    Xr[r][f] = s;
  }
  __syncthreads();

  const float4* Wr = reinterpret_cast<const float4*>(W + (size_t)t * NF);
  float accr[8];
  #pragma unroll
  for (int r = 0; r < 8; ++r) accr[r] = 0.f;

  for (int f4 = 0; f4 < NF / 4; ++f4) {
    float4 w = Wr[f4];
    #pragma unroll
    for (int r = 0; r < 8; ++r) {
      float4 xv = *reinterpret_cast<const float4*>(&Xr[r][f4 * 4]);
      accr[r] += xv.x * w.x + xv.y * w.y + xv.z * w.z + xv.w * w.w;
    }
  }
  #pragma unroll
  for (int r = 0; r < 8; ++r)
    out[(size_t)(mb + r) * NC + t] = accr[r];
}

extern "C" void kernel_launch(void* const* d_in, const int* in_sizes, int n_in,
                              void* d_out, int out_size, void* d_ws, size_t ws_size,
                              hipStream_t stream) {
  const float* x = (const float*)d_in[0];
  const float* w = (const float*)d_in[1];
  float* out = (float*)d_out;

  unsigned short* T = (unsigned short*)d_ws;
  const size_t t_bytes = (size_t)NF * V_DIM * sizeof(unsigned short); // 8,192,000
  float* P = (float*)((char*)d_ws + t_bytes);
  const size_t p_split_bytes = (size_t)M_TOT * NF * sizeof(float);    // 2 MiB

  int NS = 24;  // 768 blocks = exactly 3/CU; must stay a multiple of 8 for the swizzle
  while (NS > 8 && ws_size < t_bytes + (size_t)NS * p_split_bytes) NS -= 8;

  build_table<<<dim3(2000), dim3(256), 0, stream>>>(T);
  gemm1<<<dim3(32 * NS), dim3(THREADS), 0, stream>>>(x, T, P, NS);
  gemm2<<<dim3(M_TOT / 8), dim3(256), 0, stream>>>(P, w, out, NS);
}

// Round 3
// 191.006 us; speedup vs baseline: 1.6434x; 1.6434x over previous
//
#include <hip/hip_runtime.h>
#include <stdint.h>

#define V_DIM 32000
#define M_TOT 4096      // B*S
#define NF 128          // 2*n_freq
#define NC 256          // channels
#define BM 128
#define BK 32
#define SSTR 130        // slot stride per kg-plane (slots of 16B); 2-way max on r/w (free)
#define THREADS 256

typedef __bf16 bf16x8 __attribute__((ext_vector_type(8)));
typedef float f32x4 __attribute__((ext_vector_type(4)));

__device__ __forceinline__ unsigned short f2bf(float f) {
  unsigned int u = __float_as_uint(f);
  u += 0x7FFFu + ((u >> 16) & 1u);
  return (unsigned short)(u >> 16);
}

__device__ __forceinline__ int4 pack8(float4 lo, float4 hi) {
  union { unsigned short us[8]; int4 v; } u;
  u.us[0] = f2bf(lo.x); u.us[1] = f2bf(lo.y);
  u.us[2] = f2bf(lo.z); u.us[3] = f2bf(lo.w);
  u.us[4] = f2bf(hi.x); u.us[5] = f2bf(hi.y);
  u.us[6] = f2bf(hi.z); u.us[7] = f2bf(hi.w);
  return u.v;
}

// ---------------- Stage 0: DFT basis table in THREAD-STAGING order ----------------
// T_stage[c][q*256 + t] = 8 bf16: element e -> T_logical[row][c*32 + kg*8 + e]
//   where row = (t>>2) + 64*q, kg = t&3,
//   T_logical[f][v] = cos(2pi(f+1)v/V) for f<64, -sin(2pi(f-63)v/V) for f>=64.
// So gemm1 thread t loads chunk c at [c*4096 + t*8] and [c*4096 + (256+t)*8]:
// fully coalesced, and the int4 goes to LDS untouched.
__global__ __launch_bounds__(256) void build_table(unsigned short* __restrict__ T) {
  int id = blockIdx.x * 256 + threadIdx.x;        // slot id, 512 per chunk
  if (id >= 512 * (V_DIM / BK)) return;           // 512000
  int c = id >> 9;
  int r = id & 511;
  int q = r >> 8;
  int tt = r & 255;
  int row = (tt >> 2) + 64 * q;
  int kg = tt & 3;
  int k = (row < 64) ? (row + 1) : (row - 63);
  bool is_cos = (row < 64);
  int vb = c * 32 + kg * 8;
  const float w0 = 6.283185307179586f / (float)V_DIM;
  union { unsigned short us[8]; int4 v; } u;
  #pragma unroll
  for (int e = 0; e < 8; ++e) {
    int m = (k * (vb + e)) % V_DIM;               // exact range reduction
    float s, cc;
    __sincosf((float)m * w0, &s, &cc);
    u.us[e] = f2bf(is_cos ? cc : -s);
  }
  *reinterpret_cast<int4*>(T + (size_t)id * 8) = u.v;
}

// ---------------- Stage 1: P[ks] = x_chunk @ T_chunk^T (bf16 MFMA, fp32 acc)
// R1-style schedule: all global loads at top of step, consumed mid-step
// (pack -> ds_write), so the end-of-step barrier drain is nearly empty.
__global__ __launch_bounds__(THREADS) void gemm1(
    const float* __restrict__ x, const unsigned short* __restrict__ T,
    float* __restrict__ P, int NS) {
  __shared__ __align__(16) unsigned short As[2][4 * SSTR * 8];  // 8320 B / buf
  __shared__ __align__(16) unsigned short Bs[2][4 * SSTR * 8];

  // XCD-balanced swizzle: block b -> xcd j = b&7; xcd j owns ks in {j, j+8, ...}
  const int b = blockIdx.x;
  const int j = b & 7, i = b >> 3;
  const int ks = j + 8 * (i >> 5);
  const int mt = i & 31;
  const int m0 = mt * BM;

  const int total_steps = V_DIM / BK;   // 1000
  const int base = total_steps / NS;
  const int rem = total_steps % NS;
  const int steps = base + (ks < rem ? 1 : 0);
  const int start = ks * base + (ks < rem ? ks : rem);

  const int t = threadIdx.x;
  const int lane = t & 63;
  const int wave = t >> 6;
  const int wm = wave >> 1, wn = wave & 1;
  const int kgl = lane >> 4, rl = lane & 15;

  const int kg_t = t & 3;
  const int row_t = t >> 2;
  const int slot0 = kg_t * SSTR + row_t;
  const int slot1 = slot0 + 64;

  const float* xa0 = x + (size_t)(m0 + row_t) * V_DIM + kg_t * 8 + (size_t)start * BK;
  const float* xa1 = xa0 + (size_t)64 * V_DIM;
  const unsigned short* Tc = T + (size_t)start * 4096;

  f32x4 acc[4][4];
  #pragma unroll
  for (int a = 0; a < 4; ++a)
    #pragma unroll
    for (int c = 0; c < 4; ++c)
      acc[a][c] = (f32x4){0.f, 0.f, 0.f, 0.f};

  // ---- prologue: stage step 0 into buf0
  {
    float4 a0 = *reinterpret_cast<const float4*>(xa0);
    float4 a1 = *reinterpret_cast<const float4*>(xa0 + 4);
    float4 a2 = *reinterpret_cast<const float4*>(xa1);
    float4 a3 = *reinterpret_cast<const float4*>(xa1 + 4);
    int4 b0 = *reinterpret_cast<const int4*>(Tc + t * 8);
    int4 b1 = *reinterpret_cast<const int4*>(Tc + (256 + t) * 8);
    *reinterpret_cast<int4*>(&As[0][slot0 * 8]) = pack8(a0, a1);
    *reinterpret_cast<int4*>(&As[0][slot1 * 8]) = pack8(a2, a3);
    *reinterpret_cast<int4*>(&Bs[0][slot0 * 8]) = b0;
    *reinterpret_cast<int4*>(&Bs[0][slot1 * 8]) = b1;
    __syncthreads();
  }

  for (int s = 0; s < steps; ++s) {
    const int cur = s & 1, nxt = cur ^ 1;
    const bool pre = (s + 1 < steps);

    // 1) issue next step's 6 global loads first (latency overlaps the MFMAs)
    float4 a0, a1, a2, a3;
    int4 b0, b1;
    if (pre) {
      const float* xp = xa0 + (size_t)(s + 1) * BK;
      const float* xq = xa1 + (size_t)(s + 1) * BK;
      a0 = *reinterpret_cast<const float4*>(xp);
      a1 = *reinterpret_cast<const float4*>(xp + 4);
      a2 = *reinterpret_cast<const float4*>(xq);
      a3 = *reinterpret_cast<const float4*>(xq + 4);
      const unsigned short* tc = Tc + (size_t)(s + 1) * 4096;
      b0 = *reinterpret_cast<const int4*>(tc + t * 8);
      b1 = *reinterpret_cast<const int4*>(tc + (256 + t) * 8);
    }

    // 2) fragments + MFMA on current buffer
    bf16x8 bv[4];
    #pragma unroll
    for (int nf = 0; nf < 4; ++nf)
      bv[nf] = *reinterpret_cast<const bf16x8*>(
          &Bs[cur][(kgl * SSTR + wn * 64 + nf * 16 + rl) * 8]);
    #pragma unroll
    for (int mf = 0; mf < 4; ++mf) {
      bf16x8 av = *reinterpret_cast<const bf16x8*>(
          &As[cur][(kgl * SSTR + wm * 64 + mf * 16 + rl) * 8]);
      #pragma unroll
      for (int nf = 0; nf < 4; ++nf)
        acc[mf][nf] = __builtin_amdgcn_mfma_f32_16x16x32_bf16(
            av, bv[nf], acc[mf][nf], 0, 0, 0);
    }

    // 3) consume the loads (vmcnt wait lands here, covered by MFMA issue above)
    if (pre) {
      *reinterpret_cast<int4*>(&As[nxt][slot0 * 8]) = pack8(a0, a1);
      *reinterpret_cast<int4*>(&As[nxt][slot1 * 8]) = pack8(a2, a3);
      *reinterpret_cast<int4*>(&Bs[nxt][slot0 * 8]) = b0;
      *reinterpret_cast<int4*>(&Bs[nxt][slot1 * 8]) = b1;
    }
    __syncthreads();
  }

  // ---- epilogue: partial tile [128 x 128] for this k-split
  float* Pp = P + ((size_t)ks * M_TOT + m0) * NF;
  const int r0 = (lane >> 4) * 4;
  const int col = lane & 15;
  #pragma unroll
  for (int mf = 0; mf < 4; ++mf)
    #pragma unroll
    for (int nf = 0; nf < 4; ++nf)
      #pragma unroll
      for (int q = 0; q < 4; ++q) {
        int row = wm * 64 + mf * 16 + r0 + q;
        int n = wn * 64 + nf * 16 + col;
        Pp[(size_t)row * NF + n] = acc[mf][nf][q];
      }
}

// ---------------- Stage 2: out = (sum_s P[s]) @ W^T ----------------
__global__ __launch_bounds__(256) void gemm2(
    const float* __restrict__ P, const float* __restrict__ W,
    float* __restrict__ out, int NS) {
  __shared__ __align__(16) float Xr[8][NF];
  const int mb = blockIdx.x * 8;
  const int t = threadIdx.x;

  #pragma unroll
  for (int i = 0; i < 4; ++i) {
    int idx = t + i * 256;           // 8 rows x 128 freqs
    int r = idx >> 7, f = idx & 127;
    float s = 0.f;
    for (int sp = 0; sp < NS; ++sp)
      s += P[((size_t)sp * M_TOT + mb + r) * NF + f];
    Xr[r][f] = s;
  }
  __syncthreads();

  const float4* Wr = reinterpret_cast<const float4*>(W + (size_t)t * NF);
  float accr[8];
  #pragma unroll
  for (int r = 0; r < 8; ++r) accr[r] = 0.f;

  for (int f4 = 0; f4 < NF / 4; ++f4) {
    float4 w = Wr[f4];
    #pragma unroll
    for (int r = 0; r < 8; ++r) {
      float4 xv = *reinterpret_cast<const float4*>(&Xr[r][f4 * 4]);
      accr[r] += xv.x * w.x + xv.y * w.y + xv.z * w.z + xv.w * w.w;
    }
  }
  #pragma unroll
  for (int r = 0; r < 8; ++r)
    out[(size_t)(mb + r) * NC + t] = accr[r];
}

extern "C" void kernel_launch(void* const* d_in, const int* in_sizes, int n_in,
                              void* d_out, int out_size, void* d_ws, size_t ws_size,
                              hipStream_t stream) {
  const float* x = (const float*)d_in[0];
  const float* w = (const float*)d_in[1];
  float* out = (float*)d_out;

  unsigned short* T = (unsigned short*)d_ws;
  const size_t t_bytes = (size_t)NF * V_DIM * sizeof(unsigned short); // 8,192,000
  float* P = (float*)((char*)d_ws + t_bytes);
  const size_t p_split_bytes = (size_t)M_TOT * NF * sizeof(float);    // 2 MiB

  // 32 splits -> 1024 blocks = 4/CU (LDS 33.3KB allows 4). Multiple of 8 for swizzle.
  int NS = 32;
  while (NS > 8 && ws_size < t_bytes + (size_t)NS * p_split_bytes) NS -= 8;

  build_table<<<dim3(2000), dim3(256), 0, stream>>>(T);
  gemm1<<<dim3(32 * NS), dim3(THREADS), 0, stream>>>(x, T, P, NS);
  gemm2<<<dim3(M_TOT / 8), dim3(256), 0, stream>>>(P, w, out, NS);
}